// Round 1
// 81.779 us; speedup vs baseline: 1.0106x; 1.0106x over previous
//
#include <hip/hip_runtime.h>

// CategorySpecificMLP: out = relu(x @ W1[cat] + b1[cat]) @ W2[cat] + b2[cat]
// N=8192, C=100, D=128, H=128, O=64, fp32.
//
// R9 (on R8): kill every address-taken local array / pointer-select that can
// defeat SROA (rule #20: demoted arrays -> scratch -> ~500cy round trips).
//  - split8v takes ext_vector float8 BY VALUE; no float* into register arrays.
//  - W1/W2 loaded into floatx8 SSA values (same issue point as R8: after the
//    cat_id count, so the scan still waits on only 8 loads), then pre-split
//    ONCE into short8 hi/lo regs right after the scan (latency covered).
//  - chunk loop contains zero W splits and zero pointer ternaries.
// MFMA math identical to R5-R8 (absmax 4.9e-4): bf16 hi/lo split, 3 products
// (lo*lo dropped), frag-major LDS, 16x16x32 layouts (m89/m91).

#define N_TOK 8192
#define C_CAT 100
#define D_IN  128
#define H_MID 128
#define O_OUT 64
#define NCHUNK 2
#define GRID (C_CAT * NCHUNK)   // 200 blocks <= 256 CUs: one round

typedef __attribute__((ext_vector_type(8))) short short8;   // 8 bf16
typedef __attribute__((ext_vector_type(8))) float floatx8;  // 8 fp32
typedef __attribute__((ext_vector_type(4))) float floatx4;  // 4 fp32 acc

// exact split: hi = trunc-bf16 (exact), r = f - hi (exact), lo = RNE-bf16(r)
__device__ __forceinline__ void bf16_split(float f, short& hi, short& lo) {
  unsigned b  = __builtin_bit_cast(unsigned, f);
  unsigned hb = b & 0xFFFF0000u;
  hi = (short)(hb >> 16);
  float r = f - __builtin_bit_cast(float, hb);
  unsigned rb = __builtin_bit_cast(unsigned, r);
  lo = (short)((rb + 0x7FFFu + ((rb >> 16) & 1u)) >> 16);
}

// by-value vector split: pure SSA, nothing address-taken
__device__ __forceinline__ void split8v(floatx8 v, short8& h8, short8& l8) {
  #pragma unroll
  for (int j = 0; j < 8; ++j) {
    short hh, ll; bf16_split(v[j], hh, ll);
    h8[j] = hh; l8[j] = ll;
  }
}

__global__ __launch_bounds__(256, 1) void mlp_kernel(
    const float* __restrict__ x,  const int* __restrict__ cat_ids,
    const float* __restrict__ W1, const float* __restrict__ b1,
    const float* __restrict__ W2, const float* __restrict__ b2,
    float* __restrict__ out) {
  int bid  = blockIdx.x;
  int cat  = bid >> 1;
  int j0   = bid & 1;
  int tid  = threadIdx.x;
  int lane = tid & 63;
  int wv   = tid >> 6;            // wave 0..3

  // frag-major LDS: frag f at short8 slots [f*64, f*64+64), lane L at +L.
  __shared__ __align__(16) short XF[2][8192];  // X frags -> H frags (32 KB)
  __shared__ int toks[64];
  __shared__ int wsum[4];

  // ======== 1) cat_ids loads FIRST: count only waits on these 8 ===========
  const int4* cid4 = (const int4*)cat_ids;
  int4 cv[8];
  #pragma unroll
  for (int k = 0; k < 8; ++k) cv[k] = cid4[tid + (k << 8)];   // coalesced

  int mycnt = 0;
  #pragma unroll
  for (int k = 0; k < 8; ++k)
    mycnt += (cv[k].x == cat) + (cv[k].y == cat) + (cv[k].z == cat) + (cv[k].w == cat);

  // ======== 2) W/bias loads issue now (float SSA values, split later) ======
  const float* W1c = W1 + (size_t)cat * (D_IN * H_MID);
  floatx8 w1fa[4], w1fb[4];          // unrolled-constant indexing only
  #pragma unroll
  for (int p = 0; p < 4; ++p) {
    int f   = (p << 2) + wv;
    int nt  = f & 7;                       // wv or wv+4
    int ksl = f >> 3;
    int n   = (nt << 4) + (lane & 15);
    int kb  = (ksl << 5) + ((lane >> 4) << 3);
    #pragma unroll
    for (int j = 0; j < 8; ++j) {
      w1fa[p][j] = W1c[(size_t)(kb + j) * H_MID + n];
      w1fb[p][j] = W1c[(size_t)(64 + kb + j) * H_MID + n];
    }
  }
  const float* W2c = W2 + (size_t)cat * (H_MID * O_OUT);
  floatx8 w2f[4];
  {
    int n = (wv << 4) + (lane & 15);
    #pragma unroll
    for (int p = 0; p < 4; ++p) {
      int kb = (p << 5) + ((lane >> 4) << 3);
      #pragma unroll
      for (int j = 0; j < 8; ++j)
        w2f[p][j] = W2c[(size_t)(kb + j) * O_OUT + n];
    }
  }
  float b1v[2];
  #pragma unroll
  for (int ntl = 0; ntl < 2; ++ntl)
    b1v[ntl] = b1[(size_t)cat * H_MID + ((wv + (ntl << 2)) << 4) + (lane & 15)];
  float b2v = b2[(size_t)cat * O_OUT + (wv << 4) + (lane & 15)];

  // ======== 3) shfl wave-scan + single barrier =============================
  int s = mycnt;                           // inclusive scan within wave
  #pragma unroll
  for (int off = 1; off < 64; off <<= 1) {
    int u = __shfl_up(s, off, 64);
    if (lane >= off) s += u;
  }
  if (lane == 63) wsum[wv] = s;
  __syncthreads();
  int base = 0;
  #pragma unroll
  for (int w = 0; w < 4; ++w) base += (w < wv) ? wsum[w] : 0;
  int ebase = base + s - mycnt;            // exclusive global rank (tid-major)
  int TOT   = wsum[0] + wsum[1] + wsum[2] + wsum[3];

  // ======== 4) pre-split W once: hi/lo bf16 regs (load latency covered) ====
  // layer1 mapping: (ksg<2 ? w1a : w1b)[2*(ksg&1)+ntl]  ==  w1h/w1l[ksg][ntl]
  short8 w1h[4][2], w1l[4][2];
  #pragma unroll
  for (int p = 0; p < 4; ++p) {
    split8v(w1fa[p], w1h[p >> 1][p & 1],       w1l[p >> 1][p & 1]);
    split8v(w1fb[p], w1h[2 + (p >> 1)][p & 1], w1l[2 + (p >> 1)][p & 1]);
  }
  short8 w2h[4], w2l[4];
  #pragma unroll
  for (int ks = 0; ks < 4; ++ks) split8v(w2f[ks], w2h[ks], w2l[ks]);

  // ======== per-chunk MLP ==================================================
  for (int chunk = j0; (chunk << 6) < TOT; chunk += NCHUNK) {
    int ccnt = min(64, TOT - (chunk << 6));
    __syncthreads();                       // A: prev-iter toks readers done
    {                                      // scatter my matches in rank window
      int r = ebase, lo = chunk << 6;
      #pragma unroll
      for (int k = 0; k < 8; ++k) {
        int4 v = cv[k];
        int p = (tid + (k << 8)) << 2;
        if (v.x == cat) { int rel = r - lo; if ((unsigned)rel < 64u) toks[rel] = p;     ++r; }
        if (v.y == cat) { int rel = r - lo; if ((unsigned)rel < 64u) toks[rel] = p + 1; ++r; }
        if (v.z == cat) { int rel = r - lo; if ((unsigned)rel < 64u) toks[rel] = p + 2; ++r; }
        if (v.w == cat) { int rel = r - lo; if ((unsigned)rel < 64u) toks[rel] = p + 3; ++r; }
      }
    }
    __syncthreads();                       // B: toks visible

    // ---- X gather + stage frags (ks=p, mt=wv) ----
    int mrow = (wv << 4) + (lane & 15);
    int tok  = (mrow < ccnt) ? toks[mrow] : 0;   // clamp: padded rows read row 0
    const float* xr = x + (size_t)tok * D_IN + ((lane >> 4) << 3);
    float4 xa[4], xb[4];                   // all 8 loads issue before splits
    #pragma unroll
    for (int p = 0; p < 4; ++p) {
      xa[p] = *(const float4*)(xr + (p << 5));
      xb[p] = *(const float4*)(xr + (p << 5) + 4);
    }
    #pragma unroll
    for (int p = 0; p < 4; ++p) {
      floatx8 xv;
      xv[0] = xa[p].x; xv[1] = xa[p].y; xv[2] = xa[p].z; xv[3] = xa[p].w;
      xv[4] = xb[p].x; xv[5] = xb[p].y; xv[6] = xb[p].z; xv[7] = xb[p].w;
      short8 h8, l8;
      split8v(xv, h8, l8);
      int f = (p << 2) + wv;
      ((short8*)XF[0])[(f << 6) + lane] = h8;
      ((short8*)XF[1])[(f << 6) + lane] = l8;
    }
    __syncthreads();                       // C: XF visible

    // ---- layer1: A from LDS, B from pre-split registers ----
    floatx4 acc[4][2];
    #pragma unroll
    for (int mt = 0; mt < 4; ++mt)
      #pragma unroll
      for (int ntl = 0; ntl < 2; ++ntl) acc[mt][ntl] = 0.f;

    #pragma unroll
    for (int ksg = 0; ksg < 4; ++ksg) {
      short8 ah[4], al[4];
      #pragma unroll
      for (int mt = 0; mt < 4; ++mt) {
        ah[mt] = ((short8*)XF[0])[(((ksg << 2) + mt) << 6) + lane];
        al[mt] = ((short8*)XF[1])[(((ksg << 2) + mt) << 6) + lane];
      }
      #pragma unroll
      for (int mt = 0; mt < 4; ++mt)
        #pragma unroll
        for (int ntl = 0; ntl < 2; ++ntl) {
          acc[mt][ntl] = __builtin_amdgcn_mfma_f32_16x16x32_bf16(ah[mt], w1h[ksg][ntl], acc[mt][ntl], 0, 0, 0);
          acc[mt][ntl] = __builtin_amdgcn_mfma_f32_16x16x32_bf16(ah[mt], w1l[ksg][ntl], acc[mt][ntl], 0, 0, 0);
          acc[mt][ntl] = __builtin_amdgcn_mfma_f32_16x16x32_bf16(al[mt], w1h[ksg][ntl], acc[mt][ntl], 0, 0, 0);
        }
    }
    __syncthreads();                       // D: XF reads done before H writes

    // ---- h epilogue: bias+relu+split -> H frags in XF ----
    #pragma unroll
    for (int ntl = 0; ntl < 2; ++ntl) {
      int ntile = wv + (ntl << 2);
      int n = (ntile << 4) + (lane & 15);
      #pragma unroll
      for (int mt = 0; mt < 4; ++mt) {
        #pragma unroll
        for (int r = 0; r < 4; ++r) {
          float hfull = fmaxf(acc[mt][ntl][r] + b1v[ntl], 0.f);
          short hh, hl; bf16_split(hfull, hh, hl);
          int m  = (mt << 4) + ((lane >> 4) << 2) + r;
          int f2 = ((n >> 5) << 2) + mt;             // (ks2 = n/32, mt)
          int L2 = (((n >> 3) & 3) << 4) + (m & 15);
          int sa = (f2 << 9) + (L2 << 3) + (n & 7);
          XF[0][sa] = hh; XF[1][sa] = hl;
        }
      }
    }
    __syncthreads();                       // E: H visible

    // ---- layer2: A (H) from LDS, B from pre-split registers ----
    floatx4 acc2[4];
    #pragma unroll
    for (int mt = 0; mt < 4; ++mt) acc2[mt] = 0.f;

    #pragma unroll
    for (int ks = 0; ks < 4; ++ks) {
      #pragma unroll
      for (int mt = 0; mt < 4; ++mt) {
        short8 ah = ((short8*)XF[0])[(((ks << 2) + mt) << 6) + lane];
        short8 al = ((short8*)XF[1])[(((ks << 2) + mt) << 6) + lane];
        acc2[mt] = __builtin_amdgcn_mfma_f32_16x16x32_bf16(ah, w2h[ks], acc2[mt], 0, 0, 0);
        acc2[mt] = __builtin_amdgcn_mfma_f32_16x16x32_bf16(ah, w2l[ks], acc2[mt], 0, 0, 0);
        acc2[mt] = __builtin_amdgcn_mfma_f32_16x16x32_bf16(al, w2h[ks], acc2[mt], 0, 0, 0);
      }
    }

    // ---- store: row m=(lane>>4)*4+r+16mt, col n=lane&15+16wv ----
    {
      int n2 = (wv << 4) + (lane & 15);
      #pragma unroll
      for (int mt = 0; mt < 4; ++mt) {
        #pragma unroll
        for (int r = 0; r < 4; ++r) {
          int m = (mt << 4) + ((lane >> 4) << 2) + r;
          if (m < ccnt)
            out[(size_t)toks[m] * O_OUT + n2] = acc2[mt][r] + b2v;
        }
      }
    }
  }
}

extern "C" void kernel_launch(void* const* d_in, const int* in_sizes, int n_in,
                              void* d_out, int out_size, void* d_ws, size_t ws_size,
                              hipStream_t stream) {
  const float* x       = (const float*)d_in[0];
  const int*   cat_ids = (const int*)  d_in[1];
  const float* W1      = (const float*)d_in[2];
  const float* b1      = (const float*)d_in[3];
  const float* W2      = (const float*)d_in[4];
  const float* b2      = (const float*)d_in[5];
  float* out = (float*)d_out;

  mlp_kernel<<<GRID, 256, 0, stream>>>(x, cat_ids, W1, b1, W2, b2, out);
}